// Round 12
// baseline (83.272 us; speedup 1.0000x reference)
//
#include <hip/hip_runtime.h>
#include <stdint.h>

typedef unsigned short ushort_t;
typedef short short8 __attribute__((ext_vector_type(8)));
typedef float float4_ __attribute__((ext_vector_type(4)));
typedef unsigned short u16x8 __attribute__((ext_vector_type(8)));

#define INF_ 10000.0f
#define BATCH 8
#define SEQLEN 512
#define HIDDEN 1024
#define HEADS 12
#define HEAD_SIZE 64
#define NOUT 1536          // HEADS * 2 * HEAD_SIZE
#define MROWS 4096         // BATCH * SEQLEN
#define BH 96              // BATCH * HEADS
#define LOGITS_N 25165824  // (8,12,512,512)
#define MASK_N   2097152   // (8,1,512,512)

// ---- module-scope device scratch ----
__device__ __align__(16) ushort_t g_A [(size_t)MROWS * HIDDEN];           // 8 MB bf16
__device__ __align__(16) ushort_t g_Wt[(size_t)NOUT * HIDDEN];            // 3 MB bf16
__device__ __align__(16) ushort_t g_Q[(size_t)BH * SEQLEN * HEAD_SIZE];   // 6 MB
__device__ __align__(16) ushort_t g_K[(size_t)BH * SEQLEN * HEAD_SIZE];   // 6 MB
__device__ __align__(16) float    g_tab[SEQLEN * 32 * 2];                 // 128 KB

__device__ __forceinline__ ushort_t f2bf(float f) {
    unsigned u = __builtin_bit_cast(unsigned, f);
    unsigned r = u + 0x7FFFu + ((u >> 16) & 1u);
    return (ushort_t)(r >> 16);
}

// async global->LDS 16B (direct-to-shared DMA; LDS dest wave-uniform base + lane*16)
__device__ __forceinline__ void gload16(const ushort_t* g, ushort_t* l) {
    __builtin_amdgcn_global_load_lds(
        (const __attribute__((address_space(1))) void*)g,
        (__attribute__((address_space(3))) void*)l, 16, 0, 0);
}

// ---- robust mask decoding (sniff dtype; mask is all-ones by construction) ----
__device__ __forceinline__ unsigned mask_code(const void* m) {
    unsigned u0 = ((const unsigned*)m)[0];
    unsigned u1 = ((const unsigned*)m)[1];
    if (u0 == 0x3F803F80u) return 2;
    if (u0 == 0x3F800000u) return 3;
    if (u0 == 0x01010101u) return 4;
    if (u0 == 0x00010001u) return 5;
    if (u0 == 1u && u1 == 0u) return 1;
    return 0;
}
__device__ __forceinline__ float mask_at(const void* m, unsigned code, int i) {
    switch (code) {
        case 1: return (float)((const long long*)m)[i];
        case 2: { unsigned u = (unsigned)((const ushort_t*)m)[i] << 16;
                  return __builtin_bit_cast(float, u); }
        case 3: return ((const float*)m)[i];
        case 4: return (float)((const signed char*)m)[i];
        case 5: return (float)((const short*)m)[i];
        default: return (float)((const int*)m)[i];
    }
}

// ---- A fp32 -> bf16, 8 elems/thread ----
__global__ void k_convA(const float* __restrict__ A) {
    int i = blockIdx.x * 256 + threadIdx.x;       // 0 .. 524287
    const float4_* p = (const float4_*)(A + (size_t)i * 8);
    float4_ v0 = p[0], v1 = p[1];
    u16x8 o;
    #pragma unroll
    for (int j = 0; j < 4; ++j) { o[j] = f2bf(v0[j]); o[j + 4] = f2bf(v1[j]); }
    *(u16x8*)(g_A + (size_t)i * 8) = o;
}

// ---- transpose + convert W [K][N] fp32 -> Wt [N][K] bf16 ----
__global__ void k_convWt(const float* __restrict__ W) {
    __shared__ ushort_t tile[32][33];
    int bx = blockIdx.x % 48;
    int by = blockIdx.x / 48;
    int tx = threadIdx.x & 31, ty = threadIdx.x >> 5;
    #pragma unroll
    for (int i = 0; i < 4; ++i) {
        int k = by * 32 + ty + i * 8;
        int n = bx * 32 + tx;
        tile[ty + i * 8][tx] = f2bf(W[(size_t)k * NOUT + n]);
    }
    __syncthreads();
    #pragma unroll
    for (int i = 0; i < 4; ++i) {
        int n = bx * 32 + ty + i * 8;
        int k = by * 32 + tx;
        g_Wt[(size_t)n * HIDDEN + k] = tile[tx][ty + i * 8];
    }
}

// ---- RoPE sin/cos table ----
__global__ void k_sincos() {
    int i = blockIdx.x * 256 + threadIdx.x;
    int s = i >> 5, f = i & 31;
    float inv = powf(10000.0f, -(float)(2 * f) / 64.0f);
    float ang = (float)s * inv;
    g_tab[2 * i]     = sinf(ang);
    g_tab[2 * i + 1] = cosf(ang);
}

// ---- mask output plane (fp32) ----
__global__ void k_maskout(const void* __restrict__ mask, float* __restrict__ out1) {
    int i8 = blockIdx.x * 256 + threadIdx.x;
    int base = i8 * 8;
    int b = base >> 18;
    int m = (base >> 9) & 511;
    int n0 = base & 511;
    unsigned mcode = mask_code(mask);
    float mr = mask_at(mask, mcode, b * SEQLEN + m);
    float4_ o0, o1;
    #pragma unroll
    for (int j = 0; j < 8; ++j) {
        float padv = 1.0f - mr * mask_at(mask, mcode, b * SEQLEN + n0 + j);
        float v = ((n0 + j) < m || padv > 0.0f) ? 1.0f : 0.0f;
        if (j < 4) o0[j] = v; else o1[j - 4] = v;
    }
    *(float4_*)(out1 + base)     = o0;
    *(float4_*)(out1 + base + 4) = o1;
}

// ---- GEMM1 (bf16 MFMA, global_load_lds staging) + bias + RoPE -> g_Q/g_K ----
__global__ void __launch_bounds__(256) k_gemm1(const float* __restrict__ bias) {
    __shared__ __align__(16) ushort_t sA[2][128 * 32];
    __shared__ __align__(16) ushort_t sB[2][128 * 32];
    int tid = threadIdx.x;
    int lane = tid & 63, wid = tid >> 6;
    int wm = wid >> 1, wn = wid & 1;
    int bm = (blockIdx.x & 31) * 128;
    int bn = (blockIdx.x >> 5) * 128;

    auto stage = [&](int bi, int ks) {
        #pragma unroll
        for (int i = 0; i < 2; ++i) {
            int c = tid + i * 256;                 // 0..511
            int row = c >> 2, ch = c & 3;
            gload16(g_A  + (size_t)(bm + row) * HIDDEN + ks * 32 + ch * 8,
                    sA[bi] + (size_t)c * 8);
            gload16(g_Wt + (size_t)(bn + row) * HIDDEN + ks * 32 + ch * 8,
                    sB[bi] + (size_t)c * 8);
        }
    };

    float4_ acc[4][4] = {};
    const int NT = HIDDEN / 32;
    stage(0, 0);
    __syncthreads();
    int cur = 0;
    for (int ks = 0; ks < NT; ++ks) {
        if (ks + 1 < NT) stage(cur ^ 1, ks + 1);
        short8 af[4], bfv[4];
        int kofs = (lane >> 4) * 8;
        #pragma unroll
        for (int mf = 0; mf < 4; ++mf)
            af[mf] = *(const short8*)(sA[cur] + (wm * 64 + mf * 16 + (lane & 15)) * 32 + kofs);
        #pragma unroll
        for (int nf = 0; nf < 4; ++nf)
            bfv[nf] = *(const short8*)(sB[cur] + (wn * 64 + nf * 16 + (lane & 15)) * 32 + kofs);
        #pragma unroll
        for (int mf = 0; mf < 4; ++mf)
            #pragma unroll
            for (int nf = 0; nf < 4; ++nf)
                acc[mf][nf] = __builtin_amdgcn_mfma_f32_16x16x32_bf16(af[mf], bfv[nf], acc[mf][nf], 0, 0, 0);
        __syncthreads();               // drains next-tile loads + guards buffer reuse
        cur ^= 1;
    }

    // Epilogue (validated map: N=col=lane&15, M=row=(lane>>4)*4+reg); RoPE via lane^1.
    #pragma unroll
    for (int nf = 0; nf < 4; ++nf) {
        int gn = bn + wn * 64 + nf * 16 + (lane & 15);
        float bv = bias[gn];
        int head = gn >> 7;
        int isk  = (gn >> 6) & 1;
        int d0 = gn & 63;
        int fi = d0 >> 1;
        float sgn = (gn & 1) ? 1.0f : -1.0f;
        ushort_t* dst = isk ? g_K : g_Q;
        #pragma unroll
        for (int mf = 0; mf < 4; ++mf) {
            int gm0 = bm + wm * 64 + mf * 16 + ((lane >> 4) * 4);
            #pragma unroll
            for (int r = 0; r < 4; ++r) {
                int gm = gm0 + r;
                int s = gm & (SEQLEN - 1);
                int b = gm >> 9;
                float v = acc[mf][nf][r] + bv;
                float p = __shfl_xor(v, 1, 64);
                const float* tc = g_tab + 2 * (s * 32 + fi);
                float sn = tc[0], cs = tc[1];
                float y = v * cs + sgn * p * sn;
                size_t o = (((size_t)(b * HEADS + head)) * SEQLEN + s) * HEAD_SIZE + d0;
                dst[o] = f2bf(y);
            }
        }
    }
}

// ---- GEMM2 (bf16 MFMA, async staging): logits fp32 out + fused penalty ----
__global__ void __launch_bounds__(256) k_gemm2(const void* __restrict__ mask,
                                               float* __restrict__ out) {
    __shared__ __align__(16) ushort_t sQ[128 * 64];
    __shared__ __align__(16) ushort_t sK[128 * 64];
    __shared__ float sMr[128], sMc[128];
    int tid = threadIdx.x;
    int lane = tid & 63, wid = tid >> 6;
    int blk = blockIdx.x;
    int bh = blk >> 4;
    int t = blk & 15;
    int mt = t >> 2, nt = t & 3;
    int b = bh / HEADS;

    const ushort_t* Qb = g_Q + ((size_t)bh * SEQLEN + mt * 128) * HEAD_SIZE;
    const ushort_t* Kb = g_K + ((size_t)bh * SEQLEN + nt * 128) * HEAD_SIZE;
    #pragma unroll
    for (int i = 0; i < 4; ++i) {
        int c = tid + i * 256;                     // 0..1023
        gload16(Qb + (size_t)c * 8, sQ + (size_t)c * 8);
        gload16(Kb + (size_t)c * 8, sK + (size_t)c * 8);
    }
    unsigned mcode = mask_code(mask);
    if (tid < 128)      sMr[tid]       = mask_at(mask, mcode, b * SEQLEN + mt * 128 + tid);
    else                sMc[tid - 128] = mask_at(mask, mcode, b * SEQLEN + nt * 128 + (tid - 128));
    __syncthreads();

    int wm = wid >> 1, wn = wid & 1;
    float4_ acc[4][4] = {};
    #pragma unroll
    for (int kk = 0; kk < 2; ++kk) {
        short8 af[4], bfv[4];
        int ko = kk * 32 + (lane >> 4) * 8;
        #pragma unroll
        for (int mf = 0; mf < 4; ++mf)
            af[mf] = *(const short8*)(sQ + (wm * 64 + mf * 16 + (lane & 15)) * 64 + ko);
        #pragma unroll
        for (int nf = 0; nf < 4; ++nf)
            bfv[nf] = *(const short8*)(sK + (wn * 64 + nf * 16 + (lane & 15)) * 64 + ko);
        #pragma unroll
        for (int mf = 0; mf < 4; ++mf)
            #pragma unroll
            for (int nf = 0; nf < 4; ++nf)
                acc[mf][nf] = __builtin_amdgcn_mfma_f32_16x16x32_bf16(af[mf], bfv[nf], acc[mf][nf], 0, 0, 0);
    }

    size_t obase = (size_t)bh * SEQLEN * SEQLEN;
    #pragma unroll
    for (int mf = 0; mf < 4; ++mf) {
        #pragma unroll
        for (int nf = 0; nf < 4; ++nf) {
            int lcol = wn * 64 + nf * 16 + (lane & 15);
            int lrow0 = wm * 64 + mf * 16 + ((lane >> 4) * 4);
            int gn = nt * 128 + lcol;
            float mc = sMc[lcol];
            #pragma unroll
            for (int r = 0; r < 4; ++r) {
                int lrow = lrow0 + r;
                int gm = mt * 128 + lrow;
                float padv = 1.0f - sMr[lrow] * mc;
                bool tl = gn < gm;
                float v = (acc[mf][nf][r] - padv * INF_ - (tl ? INF_ : 0.0f)) * 0.125f;
                out[obase + (size_t)gm * SEQLEN + gn] = v;
            }
        }
    }
}

extern "C" void kernel_launch(void* const* d_in, const int* in_sizes, int n_in,
                              void* d_out, int out_size, void* d_ws, size_t ws_size,
                              hipStream_t stream) {
    const float* inp = nullptr; const float* W = nullptr;
    const float* bias = nullptr; const void* mask = nullptr;
    for (int i = 0; i < n_in; ++i) {
        switch (in_sizes[i]) {
            case MROWS * HIDDEN:  inp  = (const float*)d_in[i]; break;
            case HIDDEN * NOUT:   W    = (const float*)d_in[i]; break;
            case NOUT:            bias = (const float*)d_in[i]; break;
            case BATCH * SEQLEN:  mask = d_in[i]; break;
        }
    }
    if (!inp || !W || !bias || !mask) {
        inp  = (const float*)d_in[0];
        W    = (const float*)d_in[1];
        bias = (const float*)d_in[2];
        mask = d_in[3];
    }
    float* out = (float*)d_out;                    // fp32 output buffer
    (void)d_ws; (void)ws_size;

    k_convA<<<2048, 256, 0, stream>>>(inp);
    k_convWt<<<48 * 32, 256, 0, stream>>>(W);
    k_sincos<<<64, 256, 0, stream>>>();
    k_maskout<<<1024, 256, 0, stream>>>(mask, out + LOGITS_N);
    k_gemm1<<<384, 256, 0, stream>>>(bias);
    k_gemm2<<<16 * BH, 256, 0, stream>>>(mask, out);
}

// Round 13
// 73.928 us; speedup vs baseline: 1.1264x; 1.1264x over previous
//
#include <hip/hip_runtime.h>
#include <stdint.h>

typedef unsigned short ushort_t;
typedef short short8 __attribute__((ext_vector_type(8)));
typedef float float4_ __attribute__((ext_vector_type(4)));
typedef unsigned short u16x8 __attribute__((ext_vector_type(8)));

#define INF_ 10000.0f
#define BATCH 8
#define SEQLEN 512
#define HIDDEN 1024
#define HEADS 12
#define HEAD_SIZE 64
#define NOUT 1536          // HEADS * 2 * HEAD_SIZE
#define MROWS 4096         // BATCH * SEQLEN
#define BH 96              // BATCH * HEADS
#define LOGITS_N 25165824  // (8,12,512,512)
#define MASK_N   2097152   // (8,1,512,512)

// ---- module-scope device scratch ----
__device__ __align__(16) ushort_t g_A [(size_t)MROWS * HIDDEN];           // 8 MB bf16
__device__ __align__(16) ushort_t g_Wt[(size_t)NOUT * HIDDEN];            // 3 MB bf16
__device__ __align__(16) ushort_t g_Q[(size_t)BH * SEQLEN * HEAD_SIZE];   // 6 MB
__device__ __align__(16) ushort_t g_K[(size_t)BH * SEQLEN * HEAD_SIZE];   // 6 MB
__device__ __align__(16) float    g_tab[SEQLEN * 32 * 2];                 // 128 KB

__device__ __forceinline__ ushort_t f2bf(float f) {
    unsigned u = __builtin_bit_cast(unsigned, f);
    unsigned r = u + 0x7FFFu + ((u >> 16) & 1u);
    return (ushort_t)(r >> 16);
}

// async global->LDS 16B (LDS dest = wave-uniform base + lane*16)
__device__ __forceinline__ void gload16(const ushort_t* g, ushort_t* l) {
    __builtin_amdgcn_global_load_lds(
        (const __attribute__((address_space(1))) void*)g,
        (__attribute__((address_space(3))) void*)l, 16, 0, 0);
}

// ---- robust mask decoding ----
__device__ __forceinline__ unsigned mask_code(const void* m) {
    unsigned u0 = ((const unsigned*)m)[0];
    unsigned u1 = ((const unsigned*)m)[1];
    if (u0 == 0x3F803F80u) return 2;
    if (u0 == 0x3F800000u) return 3;
    if (u0 == 0x01010101u) return 4;
    if (u0 == 0x00010001u) return 5;
    if (u0 == 1u && u1 == 0u) return 1;
    return 0;
}
__device__ __forceinline__ float mask_at(const void* m, unsigned code, int i) {
    switch (code) {
        case 1: return (float)((const long long*)m)[i];
        case 2: { unsigned u = (unsigned)((const ushort_t*)m)[i] << 16;
                  return __builtin_bit_cast(float, u); }
        case 3: return ((const float*)m)[i];
        case 4: return (float)((const signed char*)m)[i];
        case 5: return (float)((const short*)m)[i];
        default: return (float)((const int*)m)[i];
    }
}

// ---- fused prep: convA (2048 blk) | convWt (1536 blk) | sincos (64 blk) ----
__global__ void k_prep(const float* __restrict__ A, const float* __restrict__ W) {
    __shared__ ushort_t tile[32][33];
    int bid = blockIdx.x;
    int tid = threadIdx.x;
    if (bid < 2048) {
        // A fp32 -> bf16, 8 elems/thread
        int i = bid * 256 + tid;
        const float4_* p = (const float4_*)(A + (size_t)i * 8);
        float4_ v0 = p[0], v1 = p[1];
        u16x8 o;
        #pragma unroll
        for (int j = 0; j < 4; ++j) { o[j] = f2bf(v0[j]); o[j + 4] = f2bf(v1[j]); }
        *(u16x8*)(g_A + (size_t)i * 8) = o;
    } else if (bid < 2048 + 1536) {
        // W [K][N] fp32 -> Wt [N][K] bf16 (LDS-tiled transpose)
        int bb = bid - 2048;
        int bx = bb % 48;
        int by = bb / 48;
        int tx = tid & 31, ty = tid >> 5;
        #pragma unroll
        for (int i = 0; i < 4; ++i) {
            int k = by * 32 + ty + i * 8;
            int n = bx * 32 + tx;
            tile[ty + i * 8][tx] = f2bf(W[(size_t)k * NOUT + n]);
        }
        __syncthreads();
        #pragma unroll
        for (int i = 0; i < 4; ++i) {
            int n = bx * 32 + ty + i * 8;
            int k = by * 32 + tx;
            g_Wt[(size_t)n * HIDDEN + k] = tile[tx][ty + i * 8];
        }
    } else {
        // RoPE sin/cos table
        int i = (bid - 3584) * 256 + tid;         // 0 .. 16383
        int s = i >> 5, f = i & 31;
        float inv = powf(10000.0f, -(float)(2 * f) / 64.0f);
        float ang = (float)s * inv;
        g_tab[2 * i]     = sinf(ang);
        g_tab[2 * i + 1] = cosf(ang);
    }
}

// ---- GEMM1 (bf16 MFMA, 64x128 tile, gload_lds, dbuf) + bias + RoPE ----
__global__ void __launch_bounds__(256) k_gemm1(const float* __restrict__ bias) {
    __shared__ __align__(16) ushort_t sA[2][64 * 32];
    __shared__ __align__(16) ushort_t sB[2][128 * 32];
    int tid = threadIdx.x;
    int lane = tid & 63, wid = tid >> 6;
    int wm = wid >> 1, wn = wid & 1;
    int bm = (blockIdx.x & 63) * 64;              // 64 m-tiles
    int bn = (blockIdx.x >> 6) * 128;             // 12 n-tiles

    auto stage = [&](int bi, int ks) {
        {   // A: 64 rows x 32 k = 2048 elems, 1 gload16/thread
            int row = tid >> 2, ch = tid & 3;
            gload16(g_A + (size_t)(bm + row) * HIDDEN + ks * 32 + ch * 8,
                    sA[bi] + (size_t)tid * 8);
        }
        #pragma unroll
        for (int i = 0; i < 2; ++i) {             // B: 128 rows x 32 k
            int c = tid + i * 256;
            int row = c >> 2, ch = c & 3;
            gload16(g_Wt + (size_t)(bn + row) * HIDDEN + ks * 32 + ch * 8,
                    sB[bi] + (size_t)c * 8);
        }
    };

    float4_ acc[2][4] = {};
    const int NT = HIDDEN / 32;
    stage(0, 0);
    __syncthreads();
    int cur = 0;
    for (int ks = 0; ks < NT; ++ks) {
        if (ks + 1 < NT) stage(cur ^ 1, ks + 1);
        short8 af[2], bfv[4];
        int kofs = (lane >> 4) * 8;
        #pragma unroll
        for (int mf = 0; mf < 2; ++mf)
            af[mf] = *(const short8*)(sA[cur] + (wm * 32 + mf * 16 + (lane & 15)) * 32 + kofs);
        #pragma unroll
        for (int nf = 0; nf < 4; ++nf)
            bfv[nf] = *(const short8*)(sB[cur] + (wn * 64 + nf * 16 + (lane & 15)) * 32 + kofs);
        #pragma unroll
        for (int mf = 0; mf < 2; ++mf)
            #pragma unroll
            for (int nf = 0; nf < 4; ++nf)
                acc[mf][nf] = __builtin_amdgcn_mfma_f32_16x16x32_bf16(af[mf], bfv[nf], acc[mf][nf], 0, 0, 0);
        __syncthreads();
        cur ^= 1;
    }

    // Epilogue (validated map: N=col=lane&15, M=row=(lane>>4)*4+reg); RoPE via lane^1.
    #pragma unroll
    for (int nf = 0; nf < 4; ++nf) {
        int gn = bn + wn * 64 + nf * 16 + (lane & 15);
        float bv = bias[gn];
        int head = gn >> 7;
        int isk  = (gn >> 6) & 1;
        int d0 = gn & 63;
        int fi = d0 >> 1;
        float sgn = (gn & 1) ? 1.0f : -1.0f;
        ushort_t* dst = isk ? g_K : g_Q;
        #pragma unroll
        for (int mf = 0; mf < 2; ++mf) {
            int gm0 = bm + wm * 32 + mf * 16 + ((lane >> 4) * 4);
            #pragma unroll
            for (int r = 0; r < 4; ++r) {
                int gm = gm0 + r;
                int s = gm & (SEQLEN - 1);
                int b = gm >> 9;
                float v = acc[mf][nf][r] + bv;
                float p = __shfl_xor(v, 1, 64);
                const float* tc = g_tab + 2 * (s * 32 + fi);
                float sn = tc[0], cs = tc[1];
                float y = v * cs + sgn * p * sn;
                size_t o = (((size_t)(b * HEADS + head)) * SEQLEN + s) * HEAD_SIZE + d0;
                dst[o] = f2bf(y);
            }
        }
    }
}

// ---- GEMM2 (bf16 MFMA): logits fp32 + fused penalty + fused mask plane ----
__global__ void __launch_bounds__(256) k_gemm2(const void* __restrict__ mask,
                                               float* __restrict__ out) {
    __shared__ __align__(16) ushort_t sQ[128 * 64];
    __shared__ __align__(16) ushort_t sK[128 * 64];
    __shared__ float sMr[128], sMc[128];
    int tid = threadIdx.x;
    int lane = tid & 63, wid = tid >> 6;
    int blk = blockIdx.x;
    int bh = blk >> 4;
    int t = blk & 15;
    int mt = t >> 2, nt = t & 3;
    int b = bh / HEADS;
    bool writeMask = (bh - b * HEADS) == 0;       // head 0 writes the (8,1,512,512) plane

    const ushort_t* Qb = g_Q + ((size_t)bh * SEQLEN + mt * 128) * HEAD_SIZE;
    const ushort_t* Kb = g_K + ((size_t)bh * SEQLEN + nt * 128) * HEAD_SIZE;
    #pragma unroll
    for (int i = 0; i < 4; ++i) {
        int c = tid + i * 256;
        gload16(Qb + (size_t)c * 8, sQ + (size_t)c * 8);
        gload16(Kb + (size_t)c * 8, sK + (size_t)c * 8);
    }
    unsigned mcode = mask_code(mask);
    if (tid < 128)      sMr[tid]       = mask_at(mask, mcode, b * SEQLEN + mt * 128 + tid);
    else                sMc[tid - 128] = mask_at(mask, mcode, b * SEQLEN + nt * 128 + (tid - 128));
    __syncthreads();

    int wm = wid >> 1, wn = wid & 1;
    float4_ acc[4][4] = {};
    #pragma unroll
    for (int kk = 0; kk < 2; ++kk) {
        short8 af[4], bfv[4];
        int ko = kk * 32 + (lane >> 4) * 8;
        #pragma unroll
        for (int mf = 0; mf < 4; ++mf)
            af[mf] = *(const short8*)(sQ + (wm * 64 + mf * 16 + (lane & 15)) * 64 + ko);
        #pragma unroll
        for (int nf = 0; nf < 4; ++nf)
            bfv[nf] = *(const short8*)(sK + (wn * 64 + nf * 16 + (lane & 15)) * 64 + ko);
        #pragma unroll
        for (int mf = 0; mf < 4; ++mf)
            #pragma unroll
            for (int nf = 0; nf < 4; ++nf)
                acc[mf][nf] = __builtin_amdgcn_mfma_f32_16x16x32_bf16(af[mf], bfv[nf], acc[mf][nf], 0, 0, 0);
    }

    size_t obase = (size_t)bh * SEQLEN * SEQLEN;
    size_t mbase = (size_t)LOGITS_N + (size_t)b * SEQLEN * SEQLEN;
    #pragma unroll
    for (int mf = 0; mf < 4; ++mf) {
        #pragma unroll
        for (int nf = 0; nf < 4; ++nf) {
            int lcol = wn * 64 + nf * 16 + (lane & 15);
            int lrow0 = wm * 64 + mf * 16 + ((lane >> 4) * 4);
            int gn = nt * 128 + lcol;
            float mc = sMc[lcol];
            #pragma unroll
            for (int r = 0; r < 4; ++r) {
                int lrow = lrow0 + r;
                int gm = mt * 128 + lrow;
                float padv = 1.0f - sMr[lrow] * mc;
                bool tl = gn < gm;
                float v = (acc[mf][nf][r] - padv * INF_ - (tl ? INF_ : 0.0f)) * 0.125f;
                size_t off = (size_t)gm * SEQLEN + gn;
                out[obase + off] = v;
                if (writeMask)
                    out[mbase + off] = (padv > 0.0f || tl) ? 1.0f : 0.0f;
            }
        }
    }
}

extern "C" void kernel_launch(void* const* d_in, const int* in_sizes, int n_in,
                              void* d_out, int out_size, void* d_ws, size_t ws_size,
                              hipStream_t stream) {
    const float* inp = nullptr; const float* W = nullptr;
    const float* bias = nullptr; const void* mask = nullptr;
    for (int i = 0; i < n_in; ++i) {
        switch (in_sizes[i]) {
            case MROWS * HIDDEN:  inp  = (const float*)d_in[i]; break;
            case HIDDEN * NOUT:   W    = (const float*)d_in[i]; break;
            case NOUT:            bias = (const float*)d_in[i]; break;
            case BATCH * SEQLEN:  mask = d_in[i]; break;
        }
    }
    if (!inp || !W || !bias || !mask) {
        inp  = (const float*)d_in[0];
        W    = (const float*)d_in[1];
        bias = (const float*)d_in[2];
        mask = d_in[3];
    }
    float* out = (float*)d_out;                    // fp32 output buffer
    (void)d_ws; (void)ws_size;

    k_prep<<<3648, 256, 0, stream>>>(inp, W);
    k_gemm1<<<768, 256, 0, stream>>>(bias);
    k_gemm2<<<16 * BH, 256, 0, stream>>>(mask, out);
}

// Round 14
// 59.119 us; speedup vs baseline: 1.4086x; 1.2505x over previous
//
#include <hip/hip_runtime.h>
#include <stdint.h>

typedef unsigned short ushort_t;
typedef short short8 __attribute__((ext_vector_type(8)));
typedef float float4_ __attribute__((ext_vector_type(4)));
typedef unsigned short u16x8 __attribute__((ext_vector_type(8)));

#define INF_ 10000.0f
#define BATCH 8
#define SEQLEN 512
#define HIDDEN 1024
#define HEADS 12
#define HEAD_SIZE 64
#define NOUT 1536          // HEADS * 2 * HEAD_SIZE
#define MROWS 4096         // BATCH * SEQLEN
#define BH 96              // BATCH * HEADS
#define LOGITS_N 25165824  // (8,12,512,512)
#define MASK_N   2097152   // (8,1,512,512)

// ---- module-scope device scratch ----
__device__ __align__(16) ushort_t g_A [(size_t)MROWS * HIDDEN];           // 8 MB bf16
__device__ __align__(16) ushort_t g_Wt[(size_t)NOUT * HIDDEN];            // 3 MB bf16
__device__ __align__(16) ushort_t g_Q[(size_t)BH * SEQLEN * HEAD_SIZE];   // 6 MB
__device__ __align__(16) ushort_t g_K[(size_t)BH * SEQLEN * HEAD_SIZE];   // 6 MB
__device__ __align__(16) float    g_tab[SEQLEN * 32 * 2];                 // 128 KB

__device__ __forceinline__ ushort_t f2bf(float f) {
    unsigned u = __builtin_bit_cast(unsigned, f);
    unsigned r = u + 0x7FFFu + ((u >> 16) & 1u);
    return (ushort_t)(r >> 16);
}

// async global->LDS 16B (LDS dest = wave-uniform base + lane*16, linear)
__device__ __forceinline__ void gload16(const ushort_t* g, ushort_t* l) {
    __builtin_amdgcn_global_load_lds(
        (const __attribute__((address_space(1))) void*)g,
        (__attribute__((address_space(3))) void*)l, 16, 0, 0);
}

// ---- robust mask decoding ----
__device__ __forceinline__ unsigned mask_code(const void* m) {
    unsigned u0 = ((const unsigned*)m)[0];
    unsigned u1 = ((const unsigned*)m)[1];
    if (u0 == 0x3F803F80u) return 2;
    if (u0 == 0x3F800000u) return 3;
    if (u0 == 0x01010101u) return 4;
    if (u0 == 0x00010001u) return 5;
    if (u0 == 1u && u1 == 0u) return 1;
    return 0;
}
__device__ __forceinline__ float mask_at(const void* m, unsigned code, int i) {
    switch (code) {
        case 1: return (float)((const long long*)m)[i];
        case 2: { unsigned u = (unsigned)((const ushort_t*)m)[i] << 16;
                  return __builtin_bit_cast(float, u); }
        case 3: return ((const float*)m)[i];
        case 4: return (float)((const signed char*)m)[i];
        case 5: return (float)((const short*)m)[i];
        default: return (float)((const int*)m)[i];
    }
}

// ---- fused prep: convA (2048 blk) | convWt (1536 blk) | sincos (64 blk) ----
__global__ void k_prep(const float* __restrict__ A, const float* __restrict__ W) {
    __shared__ ushort_t tile[32][33];
    int bid = blockIdx.x;
    int tid = threadIdx.x;
    if (bid < 2048) {
        int i = bid * 256 + tid;
        const float4_* p = (const float4_*)(A + (size_t)i * 8);
        float4_ v0 = p[0], v1 = p[1];
        u16x8 o;
        #pragma unroll
        for (int j = 0; j < 4; ++j) { o[j] = f2bf(v0[j]); o[j + 4] = f2bf(v1[j]); }
        *(u16x8*)(g_A + (size_t)i * 8) = o;
    } else if (bid < 2048 + 1536) {
        int bb = bid - 2048;
        int bx = bb % 48;
        int by = bb / 48;
        int tx = tid & 31, ty = tid >> 5;
        #pragma unroll
        for (int i = 0; i < 4; ++i) {
            int k = by * 32 + ty + i * 8;
            int n = bx * 32 + tx;
            tile[ty + i * 8][tx] = f2bf(W[(size_t)k * NOUT + n]);
        }
        __syncthreads();
        #pragma unroll
        for (int i = 0; i < 4; ++i) {
            int n = bx * 32 + ty + i * 8;
            int k = by * 32 + tx;
            g_Wt[(size_t)n * HIDDEN + k] = tile[tx][ty + i * 8];
        }
    } else {
        int i = (bid - 3584) * 256 + tid;
        int s = i >> 5, f = i & 31;
        float inv = powf(10000.0f, -(float)(2 * f) / 64.0f);
        float ang = (float)s * inv;
        g_tab[2 * i]     = sinf(ang);
        g_tab[2 * i + 1] = cosf(ang);
    }
}

// ---- GEMM1: 64x128 tile, BK=64, XOR-swizzled LDS, gload_lds, dbuf ----
__global__ void __launch_bounds__(256) k_gemm1(const float* __restrict__ bias) {
    __shared__ __align__(16) ushort_t sA[2][64 * 64];    // 8 KB each
    __shared__ __align__(16) ushort_t sB[2][128 * 64];   // 16 KB each
    int tid = threadIdx.x;
    int lane = tid & 63, wid = tid >> 6;
    int wm = wid >> 1, wn = wid & 1;
    int bm = (blockIdx.x & 63) * 64;              // 64 m-tiles
    int bn = (blockIdx.x >> 6) * 128;             // 12 n-tiles

    // stage: LDS dest linear (slot c -> 16B), global source chunk = (c&7)^(row&7)
    auto stage = [&](int bi, int ks) {
        #pragma unroll
        for (int i = 0; i < 2; ++i) {             // A: 64 rows x 8 chunks = 512
            int c = tid + i * 256;
            int row = c >> 3, ch = (c & 7) ^ (row & 7);
            gload16(g_A + (size_t)(bm + row) * HIDDEN + ks * 64 + ch * 8,
                    sA[bi] + (size_t)c * 8);
        }
        #pragma unroll
        for (int i = 0; i < 4; ++i) {             // B: 128 rows x 8 chunks = 1024
            int c = tid + i * 256;
            int row = c >> 3, ch = (c & 7) ^ (row & 7);
            gload16(g_Wt + (size_t)(bn + row) * HIDDEN + ks * 64 + ch * 8,
                    sB[bi] + (size_t)c * 8);
        }
    };

    float4_ acc[2][4] = {};
    const int NT = HIDDEN / 64;                   // 16 iters
    stage(0, 0);
    __syncthreads();
    int cur = 0;
    for (int ks = 0; ks < NT; ++ks) {
        if (ks + 1 < NT) stage(cur ^ 1, ks + 1);
        #pragma unroll
        for (int kk = 0; kk < 2; ++kk) {
            short8 af[2], bfv[4];
            int c0 = kk * 4 + (lane >> 4);        // logical chunk 0..7
            #pragma unroll
            for (int mf = 0; mf < 2; ++mf) {
                int r = wm * 32 + mf * 16 + (lane & 15);
                af[mf] = *(const short8*)(sA[cur] + r * 64 + ((c0 ^ (r & 7)) * 8));
            }
            #pragma unroll
            for (int nf = 0; nf < 4; ++nf) {
                int r = wn * 64 + nf * 16 + (lane & 15);
                bfv[nf] = *(const short8*)(sB[cur] + r * 64 + ((c0 ^ (r & 7)) * 8));
            }
            #pragma unroll
            for (int mf = 0; mf < 2; ++mf)
                #pragma unroll
                for (int nf = 0; nf < 4; ++nf)
                    acc[mf][nf] = __builtin_amdgcn_mfma_f32_16x16x32_bf16(af[mf], bfv[nf], acc[mf][nf], 0, 0, 0);
        }
        __syncthreads();
        cur ^= 1;
    }

    // Epilogue (validated map: N=col=lane&15, M=row=(lane>>4)*4+reg); RoPE via lane^1.
    #pragma unroll
    for (int nf = 0; nf < 4; ++nf) {
        int gn = bn + wn * 64 + nf * 16 + (lane & 15);
        float bv = bias[gn];
        int head = gn >> 7;
        int isk  = (gn >> 6) & 1;
        int d0 = gn & 63;
        int fi = d0 >> 1;
        float sgn = (gn & 1) ? 1.0f : -1.0f;
        ushort_t* dst = isk ? g_K : g_Q;
        #pragma unroll
        for (int mf = 0; mf < 2; ++mf) {
            int gm0 = bm + wm * 32 + mf * 16 + ((lane >> 4) * 4);
            #pragma unroll
            for (int r = 0; r < 4; ++r) {
                int gm = gm0 + r;
                int s = gm & (SEQLEN - 1);
                int b = gm >> 9;
                float v = acc[mf][nf][r] + bv;
                float p = __shfl_xor(v, 1, 64);
                const float* tc = g_tab + 2 * (s * 32 + fi);
                float sn = tc[0], cs = tc[1];
                float y = v * cs + sgn * p * sn;
                size_t o = (((size_t)(b * HEADS + head)) * SEQLEN + s) * HEAD_SIZE + d0;
                dst[o] = f2bf(y);
            }
        }
    }
}

// ---- GEMM2: XCD-swizzled blocks, XOR-swizzled LDS, fused penalty + mask ----
__global__ void __launch_bounds__(256) k_gemm2(const void* __restrict__ mask,
                                               float* __restrict__ out) {
    __shared__ __align__(16) ushort_t sQ[128 * 64];
    __shared__ __align__(16) ushort_t sK[128 * 64];
    __shared__ float sMr[128], sMc[128];
    int tid = threadIdx.x;
    int lane = tid & 63, wid = tid >> 6;
    // bijective XCD swizzle: 1536 blocks = 8 XCDs x 192 -> same-batch heads co-locate
    int blk = (blockIdx.x & 7) * 192 + (blockIdx.x >> 3);
    int bh = blk >> 4;
    int t = blk & 15;
    int mt = t >> 2, nt = t & 3;
    int b = bh / HEADS;
    bool writeMask = (bh - b * HEADS) == 0;

    const ushort_t* Qb = g_Q + ((size_t)bh * SEQLEN + mt * 128) * HEAD_SIZE;
    const ushort_t* Kb = g_K + ((size_t)bh * SEQLEN + nt * 128) * HEAD_SIZE;
    #pragma unroll
    for (int i = 0; i < 4; ++i) {
        int c = tid + i * 256;                    // 0..1023: row = c>>3, 8 chunks/row
        int row = c >> 3, ch = (c & 7) ^ (row & 7);
        gload16(Qb + (size_t)row * 64 + ch * 8, sQ + (size_t)c * 8);
        gload16(Kb + (size_t)row * 64 + ch * 8, sK + (size_t)c * 8);
    }
    unsigned mcode = mask_code(mask);
    if (tid < 128)      sMr[tid]       = mask_at(mask, mcode, b * SEQLEN + mt * 128 + tid);
    else                sMc[tid - 128] = mask_at(mask, mcode, b * SEQLEN + nt * 128 + (tid - 128));
    __syncthreads();

    int wm = wid >> 1, wn = wid & 1;
    float4_ acc[4][4] = {};
    #pragma unroll
    for (int kk = 0; kk < 2; ++kk) {
        short8 af[4], bfv[4];
        int c0 = kk * 4 + (lane >> 4);
        #pragma unroll
        for (int mf = 0; mf < 4; ++mf) {
            int r = wm * 64 + mf * 16 + (lane & 15);
            af[mf] = *(const short8*)(sQ + r * 64 + ((c0 ^ (r & 7)) * 8));
        }
        #pragma unroll
        for (int nf = 0; nf < 4; ++nf) {
            int r = wn * 64 + nf * 16 + (lane & 15);
            bfv[nf] = *(const short8*)(sK + r * 64 + ((c0 ^ (r & 7)) * 8));
        }
        #pragma unroll
        for (int mf = 0; mf < 4; ++mf)
            #pragma unroll
            for (int nf = 0; nf < 4; ++nf)
                acc[mf][nf] = __builtin_amdgcn_mfma_f32_16x16x32_bf16(af[mf], bfv[nf], acc[mf][nf], 0, 0, 0);
    }

    size_t obase = (size_t)bh * SEQLEN * SEQLEN;
    size_t mbase = (size_t)LOGITS_N + (size_t)b * SEQLEN * SEQLEN;
    #pragma unroll
    for (int mf = 0; mf < 4; ++mf) {
        #pragma unroll
        for (int nf = 0; nf < 4; ++nf) {
            int lcol = wn * 64 + nf * 16 + (lane & 15);
            int lrow0 = wm * 64 + mf * 16 + ((lane >> 4) * 4);
            int gn = nt * 128 + lcol;
            float mc = sMc[lcol];
            #pragma unroll
            for (int r = 0; r < 4; ++r) {
                int lrow = lrow0 + r;
                int gm = mt * 128 + lrow;
                float padv = 1.0f - sMr[lrow] * mc;
                bool tl = gn < gm;
                float v = (acc[mf][nf][r] - padv * INF_ - (tl ? INF_ : 0.0f)) * 0.125f;
                size_t off = (size_t)gm * SEQLEN + gn;
                out[obase + off] = v;
                if (writeMask)
                    out[mbase + off] = (padv > 0.0f || tl) ? 1.0f : 0.0f;
            }
        }
    }
}

extern "C" void kernel_launch(void* const* d_in, const int* in_sizes, int n_in,
                              void* d_out, int out_size, void* d_ws, size_t ws_size,
                              hipStream_t stream) {
    const float* inp = nullptr; const float* W = nullptr;
    const float* bias = nullptr; const void* mask = nullptr;
    for (int i = 0; i < n_in; ++i) {
        switch (in_sizes[i]) {
            case MROWS * HIDDEN:  inp  = (const float*)d_in[i]; break;
            case HIDDEN * NOUT:   W    = (const float*)d_in[i]; break;
            case NOUT:            bias = (const float*)d_in[i]; break;
            case BATCH * SEQLEN:  mask = d_in[i]; break;
        }
    }
    if (!inp || !W || !bias || !mask) {
        inp  = (const float*)d_in[0];
        W    = (const float*)d_in[1];
        bias = (const float*)d_in[2];
        mask = d_in[3];
    }
    float* out = (float*)d_out;                    // fp32 output buffer
    (void)d_ws; (void)ws_size;

    k_prep<<<3648, 256, 0, stream>>>(inp, W);
    k_gemm1<<<768, 256, 0, stream>>>(bias);
    k_gemm2<<<16 * BH, 256, 0, stream>>>(mask, out);
}